// Round 6
// baseline (538.545 us; speedup 1.0000x reference)
//
#include <hip/hip_runtime.h>

// SparseConv2D: 32x112x112x128 fp32 NHWC, 3x3 SAME, 126 out ch x 5 taps.
// Implicit GEMM on bf16 MFMA, dense-9-tap. M=112 (one row), N=128, K=9*128.
// R9:
//  - Ain layout [row][114px][128ch] bf16 (px0/113 zero): conv_pre is a pure
//    streaming shift-copy (coalesced both sides, cvt_pk, no LDS) ~50us.
//  - conv_main nf=4 (2M x 2N waves) with B-preload FORCED by a
//    s_waitcnt vmcnt(0) scheduling fence after the 36 B loads: regalloc must
//    keep b[9][4] live (R8's failure was the compiler sinking these loads,
//    reintroducing the stage-drain). A-LDS reads halve vs R7.
//  - stage src offsets hoisted out of cc loop; LDS q-plane stride 115 pieces
//    (plane starts mod32 {0,24,16,8}) to spread residual bank conflicts.
//  - Fallback to proven R6 kernel when ws too small.

typedef __attribute__((ext_vector_type(8))) __bf16 bf16x8;
typedef __attribute__((ext_vector_type(4))) float f32x4;
typedef __attribute__((ext_vector_type(8))) unsigned short ushort8;

__device__ __forceinline__ unsigned short f2bf(float f) {
  unsigned int u = __builtin_bit_cast(unsigned int, f);
  u += 0x7fffu + ((u >> 16) & 1u);   // RNE (inputs are finite normals)
  return (unsigned short)(u >> 16);
}

__device__ __forceinline__ unsigned int cvt_pk_bf16(float lo, float hi) {
  unsigned int r;
  asm("v_cvt_pk_bf16_f32 %0, %1, %2" : "=v"(r) : "v"(lo), "v"(hi));
  return r;
}

__device__ __forceinline__ void async_copy16(void* lds, const void* g) {
  __builtin_amdgcn_global_load_lds(
      (const __attribute__((address_space(1))) unsigned int*)g,
      (__attribute__((address_space(3))) unsigned int*)lds, 16, 0, 0);
}

// ---- workspace layout ----
#define BWS_BYTES 294912
#define ROW_BYTES 29184                      // 114 px * 128 ch * 2B
#define ROW_USH   14592
#define AIN_BYTES (3584LL * ROW_BYTES)
#define WS_NEED   ((size_t)BWS_BYTES + (size_t)AIN_BYTES + (size_t)ROW_BYTES)

// Bws[p][cc][n][c] bf16: dense kernel, n in [0,128) (126..127 zero), c in [0,32)
__global__ __launch_bounds__(256) void build_B(const float* __restrict__ sk,
                                               const int* __restrict__ patterns,
                                               unsigned short* __restrict__ Bws) {
  int idx = blockIdx.x * 256 + threadIdx.x;
  if (idx >= 9 * 128 * 128) return;
  int c = idx & 127;
  int n = (idx >> 7) & 127;
  int p = idx >> 14;
  float v = 0.f;
  if (n < 126) {
#pragma unroll
    for (int j = 0; j < 5; ++j)
      if (patterns[n * 5 + j] == p) v = sk[(j * 128 + c) * 126 + n];
  }
  int cc = c >> 5, cl = c & 31;
  Bws[(((p * 4 + cc) * 128) + n) * 32 + cl] = f2bf(v);
}

// fp32 (img,y,x,128ch) -> bf16 Ain[row][114][128], px = x+1, px 0/113 zero.
// Pure streaming: reads 2KB/wave contiguous, writes 1KB/wave contiguous.
__global__ __launch_bounds__(256) void conv_pre(const float* __restrict__ in,
                                                unsigned short* __restrict__ Ain) {
  const int bid = ((blockIdx.x & 7) * 448) + (blockIdx.x >> 3);
  const float* inrow = in + (size_t)bid * 112 * 128;
  unsigned short* orow = Ain + (size_t)bid * ROW_USH;
  const int tid = threadIdx.x;
#pragma unroll
  for (int it = 0; it < 8; ++it) {
    int i = tid + it * 256;                 // [0,1824): px = i>>4, c8 = i&15
    if (i < 1824) {
      int px = i >> 4, c8 = i & 15;
      int gx = px - 1;
      uint4 u = make_uint4(0u, 0u, 0u, 0u);
      if ((unsigned)gx < 112u) {
        const float* p = inrow + ((size_t)gx * 128) + c8 * 8;
        float4 a = *(const float4*)p;
        float4 b = *(const float4*)(p + 4);
        u.x = cvt_pk_bf16(a.x, a.y);
        u.y = cvt_pk_bf16(a.z, a.w);
        u.z = cvt_pk_bf16(b.x, b.y);
        u.w = cvt_pk_bf16(b.z, b.w);
      }
      *(uint4*)(orow + (size_t)i * 8) = u;
    }
  }
}

// LDS: [buf][r(3)][q(4)][115 px-pieces][8ch], plane stride 920 ushorts.
// piece i: t = i/115, px = i - 115t, r = t>>2, q = t&3; 1380 used pieces/buf.
__global__ __launch_bounds__(256, 2) void conv_main(const unsigned short* __restrict__ Ain,
                                                    const unsigned short* __restrict__ zp,
                                                    const unsigned short* __restrict__ Bws,
                                                    const float* __restrict__ bias,
                                                    float* __restrict__ out) {
  __shared__ unsigned short Alds[2 * 11040 + 64];   // 44,288 B

  const int tid = threadIdx.x;
  const int bid = ((blockIdx.x & 7) * 448) + (blockIdx.x >> 3);
  const int y = bid % 112;
  const int lane = tid & 63;
  const int w = tid >> 6;
  const int wm = w >> 1;            // M-half: 0 -> px tiles 0..3, 1 -> 4..6
  const int wn = w & 1;             // N-half: out ch [64wn, 64wn+64)
  const int quad = lane >> 4;
  const int lrow = lane & 15;

  const unsigned short* rp1 = Ain + (size_t)bid * ROW_USH;
  const int zpOff = (int)(3584 - bid) * ROW_USH;          // zp - rp1
  const int r0Off = (y > 0)   ? -ROW_USH : zpOff;
  const int r2Off = (y < 111) ?  ROW_USH : zpOff;

  // hoisted stage source offsets (ushorts from rp1), cc adds +32 each chunk
  int soff[6];
#pragma unroll
  for (int it = 0; it < 6; ++it) {
    int i = tid + it * 256;
    int t = i / 115;
    int px = i - t * 115;
    int q = t & 3;
    int r = t >> 2;
    int off;
    if (px >= 114 || t >= 12) off = zpOff;
    else off = (r == 0 ? r0Off : (r == 1 ? 0 : r2Off)) + px * 128 + q * 8;
    soff[it] = off;
  }

  f32x4 acc[4][4];
#pragma unroll
  for (int mt = 0; mt < 4; ++mt)
#pragma unroll
    for (int j = 0; j < 4; ++j) acc[mt][j] = (f32x4)0.f;

  auto stage = [&](int cc, int buf) {
    unsigned short* dst = &Alds[buf * 11040 + tid * 8];
    const unsigned short* s = rp1 + cc * 32;
#pragma unroll
    for (int it = 0; it < 6; ++it) {
      if (it < 5 || tid < 100)                    // pieces [0,1380)
        async_copy16((void*)(dst + it * 2048), (const void*)(s + soff[it]));
    }
  };

  stage(0, 0);
  __syncthreads();

#pragma unroll 1
  for (int cc = 0; cc < 4; ++cc) {
    const int buf = cc & 1;
    // all 36 B frags (L2-hot Bws); fence forces them into registers BEFORE the
    // stage DMA is issued -> no later wait can drain the stage.
    bf16x8 b[9][4];
    const unsigned short* Bb = Bws + (size_t)cc * 4096 + (wn * 64 + lrow) * 32 + quad * 8;
#pragma unroll
    for (int p = 0; p < 9; ++p)
#pragma unroll
      for (int j = 0; j < 4; ++j)
        b[p][j] = *(const bf16x8*)(Bb + p * 16384 + j * 512);
    asm volatile("s_waitcnt vmcnt(0)" ::: "memory");

    if (cc < 3) stage(cc + 1, buf ^ 1);   // DMA in flight during the MFMAs

    const int abase0 = buf * 11040 + quad * 920 + (wm * 64 + lrow) * 8;
#pragma unroll
    for (int p = 0; p < 9; ++p) {
      const int r = p / 3;          // dy = r-1
      const int dx = p - r * 3;
      const int abase = abase0 + r * 3680 + dx * 8;
#pragma unroll
      for (int mt = 0; mt < 4; ++mt) {
        if (mt < 3 || wm == 0) {    // wave-uniform: wm1 owns 3 M-tiles
          bf16x8 a = *(const bf16x8*)&Alds[abase + mt * 128];
#pragma unroll
          for (int j = 0; j < 4; ++j)
            acc[mt][j] = __builtin_amdgcn_mfma_f32_16x16x32_bf16(a, b[p][j], acc[mt][j], 0, 0, 0);
        }
      }
    }

    if (cc < 3) __syncthreads();   // drains stage DMA (covered by 108+ MFMAs)
  }

  // epilogue: C/D layout col = lane&15 (N), row = quad*4 + reg (M)
  const int kb = wn * 64 + lrow;
  float bv[4];
#pragma unroll
  for (int j = 0; j < 4; ++j) {
    int k = kb + j * 16;
    bv[j] = bias[k < 126 ? k : 125];
  }
  float* outrow = out + (size_t)bid * 112 * 126;
#pragma unroll
  for (int mt = 0; mt < 4; ++mt) {
    if (mt < 3 || wm == 0) {
#pragma unroll
      for (int rg = 0; rg < 4; ++rg) {
        int x = wm * 64 + mt * 16 + quad * 4 + rg;
        float* o = outrow + (size_t)x * 126;
#pragma unroll
        for (int j = 0; j < 4; ++j) {
          int k = kb + j * 16;
          if (k < 126) { float v = acc[mt][j][rg] + bv[j]; o[k] = v > 0.f ? v : 0.f; }
        }
      }
    }
  }
}

// ---------------- R6 fallback (ws too small) ----------------
__global__ __launch_bounds__(256, 2) void conv_main_fb(const float* __restrict__ in,
                                                       const unsigned short* __restrict__ Bws,
                                                       const float* __restrict__ bias,
                                                       float* __restrict__ out) {
  __shared__ unsigned short AldsF[2 * 4 * 342 * 8];

  const int tid = threadIdx.x;
  const int bid = ((blockIdx.x & 7) * 448) + (blockIdx.x >> 3);
  const int nimg = bid / 112;
  const int y = bid - nimg * 112;
  const int lane = tid & 63;
  const int w = tid >> 6;
  const int quad = lane >> 4;
  const int lrow = lane & 15;

  const float* inb = in + (size_t)nimg * 112 * 112 * 128;

  f32x4 acc[7][2];
#pragma unroll
  for (int mt = 0; mt < 7; ++mt) { acc[mt][0] = (f32x4)0.f; acc[mt][1] = (f32x4)0.f; }

  float4 pf[11];
  auto loadA = [&](int cc) {
#pragma unroll
    for (int it = 0; it < 11; ++it) {
      int i = tid + it * 256;
      float4 v = make_float4(0.f, 0.f, 0.f, 0.f);
      if (i < 2736) {
        int c4 = i & 7;
        int rest = i >> 3;
        int r = rest / 114;
        int hx = rest - r * 114;
        int gy = y + r - 1;
        int gx = hx - 1;
        if ((unsigned)gy < 112u && (unsigned)gx < 112u)
          v = *(const float4*)(inb + ((size_t)gy * 112 + gx) * 128 + cc * 32 + c4 * 4);
      }
      pf[it] = v;
    }
  };
  auto writeA = [&](int b) {
#pragma unroll
    for (int it = 0; it < 11; ++it) {
      int i = tid + it * 256;
      if (i < 2736) {
        int c4 = i & 7;
        int rest = i >> 3;
        int q = c4 >> 1, h = c4 & 1;
        ushort4 s;
        s.x = f2bf(pf[it].x); s.y = f2bf(pf[it].y);
        s.z = f2bf(pf[it].z); s.w = f2bf(pf[it].w);
        *(ushort4*)&AldsF[(((b * 4 + q) * 342) + rest) * 8 + h * 4] = s;
      }
    }
  };

  loadA(0);
  writeA(0);
  __syncthreads();

#pragma unroll 1
  for (int cc = 0; cc < 4; ++cc) {
    const int cur = cc & 1;
    bf16x8 b[9][2];
#pragma unroll
    for (int p = 0; p < 9; ++p)
#pragma unroll
      for (int j = 0; j < 2; ++j)
        b[p][j] = *(const bf16x8*)(Bws +
            (((size_t)(p * 4 + cc) * 128 + w * 32 + j * 16 + lrow) * 32 + quad * 8));

    if (cc < 3) loadA(cc + 1);

    const unsigned short* Ab = &AldsF[(size_t)(cur * 4 + quad) * 2736];
#pragma unroll
    for (int p = 0; p < 9; ++p) {
      const int r = p / 3;
      const int px = p - r * 3;
      const int abase = (r * 114 + px + lrow) * 8;
#pragma unroll
      for (int mt = 0; mt < 7; ++mt) {
        bf16x8 a = *(const bf16x8*)&Ab[abase + mt * 128];
        acc[mt][0] = __builtin_amdgcn_mfma_f32_16x16x32_bf16(a, b[p][0], acc[mt][0], 0, 0, 0);
        acc[mt][1] = __builtin_amdgcn_mfma_f32_16x16x32_bf16(a, b[p][1], acc[mt][1], 0, 0, 0);
      }
    }

    if (cc < 3) {
      writeA(cur ^ 1);
      __syncthreads();
    }
  }

  const int k0 = w * 32 + lrow;
  const int k1 = k0 + 16;
  const float bv0 = bias[k0 < 126 ? k0 : 125];
  const float bv1 = bias[k1 < 126 ? k1 : 125];
  float* outrow = out + (size_t)bid * 112 * 126;
#pragma unroll
  for (int mt = 0; mt < 7; ++mt) {
#pragma unroll
    for (int rg = 0; rg < 4; ++rg) {
      int x = mt * 16 + quad * 4 + rg;
      float* o = outrow + (size_t)x * 126;
      if (k0 < 126) { float v = acc[mt][0][rg] + bv0; o[k0] = v > 0.f ? v : 0.f; }
      if (k1 < 126) { float v = acc[mt][1][rg] + bv1; o[k1] = v > 0.f ? v : 0.f; }
    }
  }
}

extern "C" void kernel_launch(void* const* d_in, const int* in_sizes, int n_in,
                              void* d_out, int out_size, void* d_ws, size_t ws_size,
                              hipStream_t stream) {
  const float* in = (const float*)d_in[0];        // (32,112,112,128) fp32
  const float* sk = (const float*)d_in[1];        // (5,128,126) fp32
  const float* bias = (const float*)d_in[2];      // (126,) fp32
  const int* patterns = (const int*)d_in[3];      // (126,5) int32
  float* out = (float*)d_out;                     // (32,112,112,126) fp32
  unsigned short* Bws = (unsigned short*)d_ws;

  build_B<<<dim3(576), dim3(256), 0, stream>>>(sk, patterns, Bws);

  if (ws_size >= WS_NEED) {
    unsigned short* Ain = (unsigned short*)((char*)d_ws + BWS_BYTES);
    unsigned short* zp  = (unsigned short*)((char*)d_ws + BWS_BYTES + AIN_BYTES);
    hipMemsetAsync(zp, 0, ROW_BYTES, stream);
    conv_pre<<<dim3(32 * 112), dim3(256), 0, stream>>>(in, Ain);
    conv_main<<<dim3(32 * 112), dim3(256), 0, stream>>>(Ain, zp, Bws, bias, out);
  } else {
    conv_main_fb<<<dim3(32 * 112), dim3(256), 0, stream>>>(in, Bws, bias, out);
  }
}

// Round 7
// 527.881 us; speedup vs baseline: 1.0202x; 1.0202x over previous
//
#include <hip/hip_runtime.h>

// SparseConv2D: 32x112x112x128 fp32 NHWC, 3x3 SAME, 126 out ch x 5 taps.
// Implicit GEMM on bf16 MFMA, dense-9-tap. M=112 (one row), N=128, K=9*128.
// R10:
//  - conv_main nf=4 (2M x 2N waves) at __launch_bounds__(256,1): the 512-reg
//    budget removes the pressure motive that made regalloc remat the B loads
//    into the MFMA loop at (256,2) (R8: sunk, R9: remat'd after the fence ->
//    stage-drain poison both times). ~240 regs used <= 256 => HW still runs
//    2 waves/SIMD. Fence after B preload kept as ordering insurance.
//  - Ain grouped layout [row][cc][q][114][8] restored (R9's [px][128] made
//    stage sources 256B-strided, uncoalesced).
//  - conv_pre: transpose-free, reads fp32 coalesced (2KB/wave), writes bf16
//    16B-scattered (stores don't stall), cvt_pk, no LDS, no barrier.

typedef __attribute__((ext_vector_type(8))) __bf16 bf16x8;
typedef __attribute__((ext_vector_type(4))) float f32x4;
typedef __attribute__((ext_vector_type(8))) unsigned short ushort8;

__device__ __forceinline__ unsigned short f2bf(float f) {
  unsigned int u = __builtin_bit_cast(unsigned int, f);
  u += 0x7fffu + ((u >> 16) & 1u);   // RNE (inputs are finite normals)
  return (unsigned short)(u >> 16);
}

__device__ __forceinline__ unsigned int cvt_pk_bf16(float lo, float hi) {
  unsigned int r;
  asm("v_cvt_pk_bf16_f32 %0, %1, %2" : "=v"(r) : "v"(lo), "v"(hi));
  return r;
}

__device__ __forceinline__ void async_copy16(void* lds, const void* g) {
  __builtin_amdgcn_global_load_lds(
      (const __attribute__((address_space(1))) unsigned int*)g,
      (__attribute__((address_space(3))) unsigned int*)lds, 16, 0, 0);
}

// ---- workspace layout ----
#define BWS_BYTES 294912
#define ROW_BYTES 29184                      // 4cc * 4q * 114 * 8ch * 2B
#define ROW_USH   14592
#define AIN_BYTES (3584LL * ROW_BYTES)
#define WS_NEED   ((size_t)BWS_BYTES + (size_t)AIN_BYTES + (size_t)ROW_BYTES)

// Bws[p][cc][n][c] bf16: dense kernel, n in [0,128) (126..127 zero), c in [0,32)
__global__ __launch_bounds__(256) void build_B(const float* __restrict__ sk,
                                               const int* __restrict__ patterns,
                                               unsigned short* __restrict__ Bws) {
  int idx = blockIdx.x * 256 + threadIdx.x;
  if (idx >= 9 * 128 * 128) return;
  int c = idx & 127;
  int n = (idx >> 7) & 127;
  int p = idx >> 14;
  float v = 0.f;
  if (n < 126) {
#pragma unroll
    for (int j = 0; j < 5; ++j)
      if (patterns[n * 5 + j] == p) v = sk[(j * 128 + c) * 126 + n];
  }
  int cc = c >> 5, cl = c & 31;
  Bws[(((p * 4 + cc) * 128) + n) * 32 + cl] = f2bf(v);
}

// fp32 (img,y,x,128ch) -> bf16 Ain[row][ccq(16)][114px][8ch], px=x+1, 0/113 zero.
// Reads coalesced (lanes 0..15 cover 512B of one px), writes 16B scattered.
__global__ __launch_bounds__(256) void conv_pre(const float* __restrict__ in,
                                                unsigned short* __restrict__ Ain) {
  const int bid = ((blockIdx.x & 7) * 448) + (blockIdx.x >> 3);
  const float* inrow = in + (size_t)bid * 112 * 128;
  unsigned short* orow = Ain + (size_t)bid * ROW_USH;
  const int tid = threadIdx.x;
#pragma unroll
  for (int it = 0; it < 8; ++it) {
    int i = tid + it * 256;                 // [0,2048); used [0,1824)
    if (i < 1824) {
      int px = i >> 4, ccq = i & 15;
      int gx = px - 1;
      uint4 u = make_uint4(0u, 0u, 0u, 0u);
      if ((unsigned)gx < 112u) {
        const float* p = inrow + (size_t)gx * 128 + ccq * 8;
        float4 a = *(const float4*)p;
        float4 b = *(const float4*)(p + 4);
        u.x = cvt_pk_bf16(a.x, a.y);
        u.y = cvt_pk_bf16(a.z, a.w);
        u.z = cvt_pk_bf16(b.x, b.y);
        u.w = cvt_pk_bf16(b.z, b.w);
      }
      *(uint4*)(orow + ((size_t)ccq * 114 + px) * 8) = u;
    }
  }
}

// LDS: [buf][r(3)][q(4)][115 px-pieces][8ch], plane stride 920 ushorts.
__global__ __launch_bounds__(256, 1) void conv_main(const unsigned short* __restrict__ Ain,
                                                    const unsigned short* __restrict__ zp,
                                                    const unsigned short* __restrict__ Bws,
                                                    const float* __restrict__ bias,
                                                    float* __restrict__ out) {
  __shared__ unsigned short Alds[2 * 11040 + 32];   // 44,224 B

  const int tid = threadIdx.x;
  const int bid = ((blockIdx.x & 7) * 448) + (blockIdx.x >> 3);
  const int y = bid % 112;
  const int lane = tid & 63;
  const int w = tid >> 6;
  const int wm = w >> 1;            // M-half: 0 -> px tiles 0..3, 1 -> 4..6
  const int wn = w & 1;             // N-half: out ch [64wn, 64wn+64)
  const int quad = lane >> 4;
  const int lrow = lane & 15;

  const unsigned short* rp1 = Ain + (size_t)bid * ROW_USH;
  const int zpOff = (int)(3584 - bid) * ROW_USH;          // zp - rp1
  const int r0Off = (y > 0)   ? -ROW_USH : zpOff;
  const int r2Off = (y < 111) ?  ROW_USH : zpOff;

  // hoisted stage source offsets (ushorts from rp1); stage adds cc*3648.
  // piece i: t = i/115 (r = t>>2, q = t&3), px = i - 115t.
  int soff[6];
#pragma unroll
  for (int it = 0; it < 6; ++it) {
    int i = tid + it * 256;
    int t = i / 115;
    int px = i - t * 115;
    int q = t & 3;
    int r = t >> 2;
    int off;
    if (px >= 114 || t >= 12) off = zpOff;
    else off = (r == 0 ? r0Off : (r == 1 ? 0 : r2Off)) + (q * 114 + px) * 8;
    soff[it] = off;
  }

  f32x4 acc[4][4];
#pragma unroll
  for (int mt = 0; mt < 4; ++mt)
#pragma unroll
    for (int j = 0; j < 4; ++j) acc[mt][j] = (f32x4)0.f;

  auto stage = [&](int cc, int buf) {
    unsigned short* dst = &Alds[buf * 11040 + tid * 8];
    const unsigned short* s = rp1 + cc * 3648;
#pragma unroll
    for (int it = 0; it < 6; ++it) {
      if (it < 5 || tid < 100)                    // pieces [0,1380)
        async_copy16((void*)(dst + it * 2048), (const void*)(s + soff[it]));
    }
  };

  stage(0, 0);
  __syncthreads();

#pragma unroll 1
  for (int cc = 0; cc < 4; ++cc) {
    const int buf = cc & 1;
    // all 36 B frags (L2-hot Bws); fence orders them BEFORE the stage DMA so
    // no later wait can drain the stage. (256,1) budget keeps them resident.
    bf16x8 b[9][4];
    const unsigned short* Bb = Bws + (size_t)cc * 4096 + (wn * 64 + lrow) * 32 + quad * 8;
#pragma unroll
    for (int p = 0; p < 9; ++p)
#pragma unroll
      for (int j = 0; j < 4; ++j)
        b[p][j] = *(const bf16x8*)(Bb + p * 16384 + j * 512);
    asm volatile("s_waitcnt vmcnt(0)" ::: "memory");

    if (cc < 3) stage(cc + 1, buf ^ 1);   // DMA in flight during the MFMAs

    const int abase0 = buf * 11040 + quad * 920 + (wm * 64 + lrow) * 8;
#pragma unroll
    for (int p = 0; p < 9; ++p) {
      const int r = p / 3;          // dy = r-1
      const int dx = p - r * 3;
      const int abase = abase0 + r * 3680 + dx * 8;
#pragma unroll
      for (int mt = 0; mt < 4; ++mt) {
        if (mt < 3 || wm == 0) {    // wave-uniform: wm1 owns 3 M-tiles
          bf16x8 a = *(const bf16x8*)&Alds[abase + mt * 128];
#pragma unroll
          for (int j = 0; j < 4; ++j)
            acc[mt][j] = __builtin_amdgcn_mfma_f32_16x16x32_bf16(a, b[p][j], acc[mt][j], 0, 0, 0);
        }
      }
    }

    if (cc < 3) __syncthreads();   // drains stage DMA (covered by the MFMAs)
  }

  // epilogue: C/D layout col = lane&15 (N), row = quad*4 + reg (M)
  const int kb = wn * 64 + lrow;
  float bv[4];
#pragma unroll
  for (int j = 0; j < 4; ++j) {
    int k = kb + j * 16;
    bv[j] = bias[k < 126 ? k : 125];
  }
  float* outrow = out + (size_t)bid * 112 * 126;
#pragma unroll
  for (int mt = 0; mt < 4; ++mt) {
    if (mt < 3 || wm == 0) {
#pragma unroll
      for (int rg = 0; rg < 4; ++rg) {
        int x = wm * 64 + mt * 16 + quad * 4 + rg;
        float* o = outrow + (size_t)x * 126;
#pragma unroll
        for (int j = 0; j < 4; ++j) {
          int k = kb + j * 16;
          if (k < 126) { float v = acc[mt][j][rg] + bv[j]; o[k] = v > 0.f ? v : 0.f; }
        }
      }
    }
  }
}

// ---------------- R6 fallback (ws too small) ----------------
__global__ __launch_bounds__(256, 2) void conv_main_fb(const float* __restrict__ in,
                                                       const unsigned short* __restrict__ Bws,
                                                       const float* __restrict__ bias,
                                                       float* __restrict__ out) {
  __shared__ unsigned short AldsF[2 * 4 * 342 * 8];

  const int tid = threadIdx.x;
  const int bid = ((blockIdx.x & 7) * 448) + (blockIdx.x >> 3);
  const int nimg = bid / 112;
  const int y = bid - nimg * 112;
  const int lane = tid & 63;
  const int w = tid >> 6;
  const int quad = lane >> 4;
  const int lrow = lane & 15;

  const float* inb = in + (size_t)nimg * 112 * 112 * 128;

  f32x4 acc[7][2];
#pragma unroll
  for (int mt = 0; mt < 7; ++mt) { acc[mt][0] = (f32x4)0.f; acc[mt][1] = (f32x4)0.f; }

  float4 pf[11];
  auto loadA = [&](int cc) {
#pragma unroll
    for (int it = 0; it < 11; ++it) {
      int i = tid + it * 256;
      float4 v = make_float4(0.f, 0.f, 0.f, 0.f);
      if (i < 2736) {
        int c4 = i & 7;
        int rest = i >> 3;
        int r = rest / 114;
        int hx = rest - r * 114;
        int gy = y + r - 1;
        int gx = hx - 1;
        if ((unsigned)gy < 112u && (unsigned)gx < 112u)
          v = *(const float4*)(inb + ((size_t)gy * 112 + gx) * 128 + cc * 32 + c4 * 4);
      }
      pf[it] = v;
    }
  };
  auto writeA = [&](int b) {
#pragma unroll
    for (int it = 0; it < 11; ++it) {
      int i = tid + it * 256;
      if (i < 2736) {
        int c4 = i & 7;
        int rest = i >> 3;
        int q = c4 >> 1, h = c4 & 1;
        ushort4 s;
        s.x = f2bf(pf[it].x); s.y = f2bf(pf[it].y);
        s.z = f2bf(pf[it].z); s.w = f2bf(pf[it].w);
        *(ushort4*)&AldsF[(((b * 4 + q) * 342) + rest) * 8 + h * 4] = s;
      }
    }
  };

  loadA(0);
  writeA(0);
  __syncthreads();

#pragma unroll 1
  for (int cc = 0; cc < 4; ++cc) {
    const int cur = cc & 1;
    bf16x8 b[9][2];
#pragma unroll
    for (int p = 0; p < 9; ++p)
#pragma unroll
      for (int j = 0; j < 2; ++j)
        b[p][j] = *(const bf16x8*)(Bws +
            (((size_t)(p * 4 + cc) * 128 + w * 32 + j * 16 + lrow) * 32 + quad * 8));

    if (cc < 3) loadA(cc + 1);

    const unsigned short* Ab = &AldsF[(size_t)(cur * 4 + quad) * 2736];
#pragma unroll
    for (int p = 0; p < 9; ++p) {
      const int r = p / 3;
      const int px = p - r * 3;
      const int abase = (r * 114 + px + lrow) * 8;
#pragma unroll
      for (int mt = 0; mt < 7; ++mt) {
        bf16x8 a = *(const bf16x8*)&Ab[abase + mt * 128];
        acc[mt][0] = __builtin_amdgcn_mfma_f32_16x16x32_bf16(a, b[p][0], acc[mt][0], 0, 0, 0);
        acc[mt][1] = __builtin_amdgcn_mfma_f32_16x16x32_bf16(a, b[p][1], acc[mt][1], 0, 0, 0);
      }
    }

    if (cc < 3) {
      writeA(cur ^ 1);
      __syncthreads();
    }
  }

  const int k0 = w * 32 + lrow;
  const int k1 = k0 + 16;
  const float bv0 = bias[k0 < 126 ? k0 : 125];
  const float bv1 = bias[k1 < 126 ? k1 : 125];
  float* outrow = out + (size_t)bid * 112 * 126;
#pragma unroll
  for (int mt = 0; mt < 7; ++mt) {
#pragma unroll
    for (int rg = 0; rg < 4; ++rg) {
      int x = mt * 16 + quad * 4 + rg;
      float* o = outrow + (size_t)x * 126;
      if (k0 < 126) { float v = acc[mt][0][rg] + bv0; o[k0] = v > 0.f ? v : 0.f; }
      if (k1 < 126) { float v = acc[mt][1][rg] + bv1; o[k1] = v > 0.f ? v : 0.f; }
    }
  }
}

extern "C" void kernel_launch(void* const* d_in, const int* in_sizes, int n_in,
                              void* d_out, int out_size, void* d_ws, size_t ws_size,
                              hipStream_t stream) {
  const float* in = (const float*)d_in[0];        // (32,112,112,128) fp32
  const float* sk = (const float*)d_in[1];        // (5,128,126) fp32
  const float* bias = (const float*)d_in[2];      // (126,) fp32
  const int* patterns = (const int*)d_in[3];      // (126,5) int32
  float* out = (float*)d_out;                     // (32,112,112,126) fp32
  unsigned short* Bws = (unsigned short*)d_ws;

  build_B<<<dim3(576), dim3(256), 0, stream>>>(sk, patterns, Bws);

  if (ws_size >= WS_NEED) {
    unsigned short* Ain = (unsigned short*)((char*)d_ws + BWS_BYTES);
    unsigned short* zp  = (unsigned short*)((char*)d_ws + BWS_BYTES + AIN_BYTES);
    hipMemsetAsync(zp, 0, ROW_BYTES, stream);
    conv_pre<<<dim3(32 * 112), dim3(256), 0, stream>>>(in, Ain);
    conv_main<<<dim3(32 * 112), dim3(256), 0, stream>>>(Ain, zp, Bws, bias, out);
  } else {
    conv_main_fb<<<dim3(32 * 112), dim3(256), 0, stream>>>(in, Bws, bias, out);
  }
}